// Round 4
// baseline (183.905 us; speedup 1.0000x reference)
//
#include <hip/hip_runtime.h>
#include <hip/hip_bf16.h>
#include <cstdint>
#include <cstddef>

#define NB 2048
#define NT 200
#define ND 64
#define NH1 128
#define NH2 64
#define NTILES 7
#define NTP 224

typedef __bf16 bf16x8 __attribute__((ext_vector_type(8)));
typedef float f32x4 __attribute__((ext_vector_type(4)));

#define MFMA16(A, Bv, C) __builtin_amdgcn_mfma_f32_16x16x32_bf16((A), (Bv), (C), 0, 0, 0)

union BF8u { __bf16 b[8]; bf16x8 v; uint4 u4; };

// sum over the 16-lane DPP row (circulant rotate-add); result in every lane
template<int N>
__device__ __forceinline__ float row_ror_add(float v) {
    int r = __builtin_amdgcn_update_dpp(0, __builtin_bit_cast(int, v),
                                        0x120 | N, 0xF, 0xF, false);
    return v + __builtin_bit_cast(float, r);
}

// prep: Qp[c][j] = (W1q+W1d)[c][j]; AbT[j][c] = (W1k-W1d)[c][j];
//       PT[j][c] = W1prod[c][j];    W2t[h2][k] = bf16(W2[k][h2])
__global__ void prep_kernel(const float* __restrict__ W1, const float* __restrict__ W2,
                            float* __restrict__ Qp, float* __restrict__ AbT,
                            float* __restrict__ PT, __bf16* __restrict__ W2t) {
    int tid = blockIdx.x * blockDim.x + threadIdx.x;
    if (tid < 64 * NH1) {
        int c = tid >> 7, j = tid & 127;
        Qp[tid] = W1[c * NH1 + j] + W1[(128 + c) * NH1 + j];
        int jj = tid >> 6, cc = tid & 63;
        AbT[tid] = W1[(64 + cc) * NH1 + jj] - W1[(128 + cc) * NH1 + jj];
        PT[tid]  = W1[(192 + cc) * NH1 + jj];
        int j2 = tid >> 7, k = tid & 127;
        W2t[tid] = (__bf16)W2[k * NH2 + j2];
    }
}

// LDS pool (22720 B):
//  [0,     17408) H1[2][32][136] bf16   (aliased by REDS[16][68] f32 in epilogue)
//  [17408, 20992) SP[4][224] f32
//  [20992, 21888) MASKF[224] f32
//  [21888, 22144) QS[64] f32
//  [22144, 22656) QHS[128] f32
//  [22656, 22720) DEN[16] f32
__global__ __launch_bounds__(256, 4)
void attn_main(const float* __restrict__ query, const float* __restrict__ key,
               const float* __restrict__ value, const int* __restrict__ mask,
               const float* __restrict__ b1, const float* __restrict__ b2,
               const float* __restrict__ Wo,
               const float* __restrict__ Qp, const float* __restrict__ AbT,
               const float* __restrict__ PT, const __bf16* __restrict__ W2t,
               float* __restrict__ out)
{
    __shared__ __align__(16) char smem[22720];
    auto H1    = (__bf16(*)[32][136])(smem);
    auto SP    = (float(*)[NTP])(smem + 17408);
    float* MASKF = (float*)(smem + 20992);
    float* QS    = (float*)(smem + 21888);
    float* QHS   = (float*)(smem + 22144);
    float* DEN   = (float*)(smem + 22656);
    float* REDS  = (float*)(smem);            // [16][68], aliases dead H1

    const int b = blockIdx.x;
    const int tid = threadIdx.x;
    const int lane = tid & 63;
    const int wave = tid >> 6;
    const int jn = lane & 15;
    const int g4 = lane >> 4;
    const int g8 = g4 * 8;
    const int tg = tid >> 4;     // 0..15
    const int dq = tid & 15;     // 0..15

    // ---- k A-fragment register staging (gather: lane owns its fragment) ----
    const float* kbase = key + (size_t)b * NT * ND;
    float4 st[8];
    bf16x8 ahi[2][2];

    auto issue_k = [&](int ti) {
        #pragma unroll
        for (int mt = 0; mt < 2; ++mt) {
            int t = ti * 32 + mt * 16 + jn;
            t = t < NT ? t : NT - 1;
            const float* rp = kbase + t * ND + g8;
            #pragma unroll
            for (int kk = 0; kk < 2; ++kk) {
                st[mt * 4 + kk * 2 + 0] = *(const float4*)(rp + kk * 32);
                st[mt * 4 + kk * 2 + 1] = *(const float4*)(rp + kk * 32 + 4);
            }
        }
    };
    auto convert_k = [&]() {
        #pragma unroll
        for (int mt = 0; mt < 2; ++mt)
        #pragma unroll
        for (int kk = 0; kk < 2; ++kk) {
            const float4 u = st[mt * 4 + kk * 2], w = st[mt * 4 + kk * 2 + 1];
            const float f[8] = {u.x, u.y, u.z, u.w, w.x, w.y, w.z, w.w};
            BF8u h;
            #pragma unroll
            for (int e = 0; e < 8; ++e) h.b[e] = (__bf16)f[e];
            ahi[mt][kk] = h.v;
        }
    };

    issue_k(0);                                       // first thing: HBM in flight

    if (tid < ND) QS[tid] = query[(size_t)b * ND + tid];
    if (tid < NTP) MASKF[tid] = (tid < NT && mask[(size_t)b * NT + tid] != 0) ? 1.f : 0.f;
    __syncthreads();

    // qh = b1 + q.(W1q+W1d)
    if (tid < NH1) {
        float a = b1[tid];
        #pragma unroll 8
        for (int c = 0; c < ND; ++c) a = fmaf(QS[c], Qp[c * NH1 + tid], a);
        QHS[tid] = a;
    }

    // GEMM1 B-frags: B_b[c][j] = AbT[j][c] + q[c]*PT[j][c], bf16 hi+lo, in regs.
    bf16x8 g1_bhi[2][2], g1_blo[2][2];
    const int jown = wave * 32;
    #pragma unroll
    for (int n = 0; n < 2; ++n) {
        const int j = jown + n * 16 + jn;
        #pragma unroll
        for (int kk = 0; kk < 2; ++kk) {
            const float* ab = AbT + j * ND + kk * 32 + g8;
            const float* pt = PT  + j * ND + kk * 32 + g8;
            float4 a0 = *(const float4*)ab, a1 = *(const float4*)(ab + 4);
            float4 p0 = *(const float4*)pt, p1 = *(const float4*)(pt + 4);
            const float va[8] = {a0.x,a0.y,a0.z,a0.w,a1.x,a1.y,a1.z,a1.w};
            const float vp[8] = {p0.x,p0.y,p0.z,p0.w,p1.x,p1.y,p1.z,p1.w};
            BF8u vh, vl;
            #pragma unroll
            for (int e = 0; e < 8; ++e) {
                const int c = kk * 32 + g8 + e;
                float v = fmaf(QS[c], vp[e], va[e]);
                __bf16 hi = (__bf16)v;
                vh.b[e] = hi;
                vl.b[e] = (__bf16)(v - (float)hi);
            }
            g1_bhi[n][kk] = vh.v;
            g1_blo[n][kk] = vl.v;
        }
    }
    // GEMM2 B-frags (plain bf16 W2t)
    bf16x8 g2_w[4];
    {
        const int j2 = wave * 16 + jn;
        #pragma unroll
        for (int kk = 0; kk < 4; ++kk)
            g2_w[kk] = *(const bf16x8*)(W2t + j2 * NH1 + kk * 32 + g8);
    }
    __syncthreads();                                   // QHS visible
    const float qh0 = QHS[jown + jn];
    const float qh1 = QHS[jown + 16 + jn];
    const float b2j = b2[wave * 16 + jn];
    const float woj = Wo[wave * 16 + jn];

    convert_k();                                       // k(0) -> frags
    issue_k(1);                                        // next tile in flight

    const float* vbase = value + (size_t)b * NT * ND + dq * 4;
    float4 vv0{}, vv1{};
    float oa0 = 0.f, oa1 = 0.f, oa2 = 0.f, oa3 = 0.f, dsum = 0.f;

    for (int ti = 0; ti < NTILES; ++ti) {
        const int p = ti & 1;
        const int t0 = ti * 32;

        // ---- GEMM1: h1 = relu(qh + k @ B_b) -> H1[p] (2 chains of 2 MFMA) ----
        #pragma unroll
        for (int mt = 0; mt < 2; ++mt) {
            #pragma unroll
            for (int n = 0; n < 2; ++n) {
                f32x4 acA = {0.f,0.f,0.f,0.f}, acB = {0.f,0.f,0.f,0.f};
                acA = MFMA16(ahi[mt][0], g1_bhi[n][0], acA);
                acB = MFMA16(ahi[mt][1], g1_bhi[n][1], acB);
                acA = MFMA16(ahi[mt][0], g1_blo[n][0], acA);
                acB = MFMA16(ahi[mt][1], g1_blo[n][1], acB);
                const float qhj = n ? qh1 : qh0;
                const int j = jown + n * 16 + jn;
                #pragma unroll
                for (int r = 0; r < 4; ++r) {
                    const int tl = mt * 16 + g4 * 4 + r;
                    H1[p][tl][j] = (__bf16)fmaxf(acA[r] + acB[r] + qhj, 0.f);
                }
            }
        }
        __syncthreads();                               // the ONE barrier per tile

        // ---- GEMM2 + score: s = relu(h1@W2 + b2) . Wo ; DPP 16-lane reduce ----
        #pragma unroll
        for (int mt = 0; mt < 2; ++mt) {
            bf16x8 h[4];
            #pragma unroll
            for (int kk = 0; kk < 4; ++kk)
                h[kk] = *(const bf16x8*)(&H1[p][mt * 16 + jn][kk * 32 + g8]);
            f32x4 cA = {0.f,0.f,0.f,0.f}, cB = {0.f,0.f,0.f,0.f};
            cA = MFMA16(h[0], g2_w[0], cA);
            cB = MFMA16(h[1], g2_w[1], cB);
            cA = MFMA16(h[2], g2_w[2], cA);
            cB = MFMA16(h[3], g2_w[3], cB);
            #pragma unroll
            for (int r = 0; r < 4; ++r) {
                float v = fmaxf(cA[r] + cB[r] + b2j, 0.f) * woj;
                v = row_ror_add<8>(v);
                v = row_ror_add<4>(v);
                v = row_ror_add<2>(v);
                v = row_ror_add<1>(v);
                if (jn == 0) SP[wave][t0 + mt * 16 + g4 * 4 + r] = v;
            }
        }

        // ---- consume tile ti-1: e = mask*exp(s); acc += e*V (V in regs) ----
        if (ti > 0) {
            const int r0 = (ti - 1) * 32 + tg, r1 = r0 + 16;
            const float s0 = SP[0][r0] + SP[1][r0] + SP[2][r0] + SP[3][r0];
            const float s1 = SP[0][r1] + SP[1][r1] + SP[2][r1] + SP[3][r1];
            const float e0 = MASKF[r0] * __expf(s0);
            const float e1 = MASKF[r1] * __expf(s1);
            oa0 = fmaf(e0, vv0.x, fmaf(e1, vv1.x, oa0));
            oa1 = fmaf(e0, vv0.y, fmaf(e1, vv1.y, oa1));
            oa2 = fmaf(e0, vv0.z, fmaf(e1, vv1.z, oa2));
            oa3 = fmaf(e0, vv0.w, fmaf(e1, vv1.w, oa3));
            dsum += e0 + e1;
        }
        // ---- V prefetch for tile ti (consumed next iter / epilogue) ----
        {
            int t = t0 + tg;       t = t < NT ? t : NT - 1;
            int t2 = t0 + tg + 16; t2 = t2 < NT ? t2 : NT - 1;
            vv0 = *(const float4*)(vbase + (size_t)t * ND);
            vv1 = *(const float4*)(vbase + (size_t)t2 * ND);
        }
        // ---- k pipeline: convert ti+1 (issued one iter ago), issue ti+2 ----
        if (ti + 1 < NTILES) {
            convert_k();
            if (ti + 2 < NTILES) issue_k(ti + 2);
        }
    }

    __syncthreads();                                   // SP(last) visible; H1 dead
    {   // consume last tile
        const int r0 = (NTILES - 1) * 32 + tg, r1 = r0 + 16;
        const float s0 = SP[0][r0] + SP[1][r0] + SP[2][r0] + SP[3][r0];
        const float s1 = SP[0][r1] + SP[1][r1] + SP[2][r1] + SP[3][r1];
        const float e0 = MASKF[r0] * __expf(s0);
        const float e1 = MASKF[r1] * __expf(s1);
        oa0 = fmaf(e0, vv0.x, fmaf(e1, vv1.x, oa0));
        oa1 = fmaf(e0, vv0.y, fmaf(e1, vv1.y, oa1));
        oa2 = fmaf(e0, vv0.z, fmaf(e1, vv1.z, oa2));
        oa3 = fmaf(e0, vv0.w, fmaf(e1, vv1.w, oa3));
        dsum += e0 + e1;
    }
    if (dq == 0) DEN[tg] = dsum;                       // identical across dq
    REDS[tg * 68 + dq * 4 + 0] = oa0;
    REDS[tg * 68 + dq * 4 + 1] = oa1;
    REDS[tg * 68 + dq * 4 + 2] = oa2;
    REDS[tg * 68 + dq * 4 + 3] = oa3;
    __syncthreads();

    if (tid < ND) {
        float den = 0.f, s = 0.f;
        #pragma unroll
        for (int g = 0; g < 16; ++g) den += DEN[g];
        #pragma unroll
        for (int g = 0; g < 16; ++g) s += REDS[g * 68 + tid];
        out[(size_t)b * ND + tid] = s / den;
    }
}

extern "C" void kernel_launch(void* const* d_in, const int* in_sizes, int n_in,
                              void* d_out, int out_size, void* d_ws, size_t ws_size,
                              hipStream_t stream) {
    const float* query = (const float*)d_in[0];
    const float* key   = (const float*)d_in[1];
    const float* value = (const float*)d_in[2];
    const int*   maskp = (const int*)d_in[3];
    const float* W1    = (const float*)d_in[4];
    const float* b1    = (const float*)d_in[5];
    const float* W2    = (const float*)d_in[6];
    const float* b2    = (const float*)d_in[7];
    const float* Wo    = (const float*)d_in[8];
    float* out = (float*)d_out;

    float* Qp  = (float*)d_ws;                 // 64*128 f32
    float* AbT = Qp + 64 * NH1;                // 128*64 f32
    float* PT  = AbT + NH1 * ND;               // 128*64 f32
    __bf16* W2t = (__bf16*)(PT + NH1 * ND);    // 64*128 bf16

    prep_kernel<<<32, 256, 0, stream>>>(W1, W2, Qp, AbT, PT, W2t);
    attn_main<<<NB, 256, 0, stream>>>(query, key, value, maskp, b1, b2, Wo,
                                      Qp, AbT, PT, W2t, out);
}